// Round 1
// baseline (646.857 us; speedup 1.0000x reference)
//
#include <hip/hip_runtime.h>
#include <hip/hip_bf16.h>

typedef __attribute__((ext_vector_type(8))) short bf16x8;
typedef __attribute__((ext_vector_type(4))) float f32x4;
typedef unsigned short ushort_t;

__device__ __forceinline__ ushort_t f2b(float f) {
    unsigned u = __builtin_bit_cast(unsigned, f);
    unsigned r = (u + 0x7FFFu + ((u >> 16) & 1u)) >> 16;
    return (ushort_t)r;
}

// ---------------- convert x (fp32 -> bf16), grid-stride over float4 ----------------
__global__ __launch_bounds__(256) void convert_x_kernel(const float* __restrict__ in,
                                                        ushort_t* __restrict__ out, int n4) {
    int i = blockIdx.x * blockDim.x + threadIdx.x;
    if (i < n4) {
        float4 f = ((const float4*)in)[i];
        ushort4 u;
        u.x = f2b(f.x); u.y = f2b(f.y); u.z = f2b(f.z); u.w = f2b(f.w);
        ((ushort4*)out)[i] = u;
    }
}

// ---------------- transpose + convert weight: W[K=1024][N=1024] fp32 -> WT[N][K] bf16 ----------------
__global__ __launch_bounds__(256) void transpose_w_kernel(const float* __restrict__ W,
                                                          ushort_t* __restrict__ WT) {
    __shared__ float t[32][33];
    int n0 = blockIdx.x * 32, k0 = blockIdx.y * 32;
    int tx = threadIdx.x, ty = threadIdx.y; // block (32,8)
    for (int i = 0; i < 4; ++i)
        t[ty + i * 8][tx] = W[(size_t)(k0 + ty + i * 8) * 1024 + n0 + tx];
    __syncthreads();
    for (int i = 0; i < 4; ++i)
        WT[(size_t)(n0 + ty + i * 8) * 1024 + k0 + tx] = f2b(t[tx][ty + i * 8]);
}

// ---------------- bf16 MFMA GEMM: C[8192][1024] = A[8192][1024] @ BT[1024][1024]^T ----------------
// BT is [N][K] (pre-transposed weight). OUT_BF16=1: bf16 out, no bias. 0: fp32 out + bias.
template <int OUT_BF16>
__global__ __launch_bounds__(256) void gemm_kernel(const ushort_t* __restrict__ A,
                                                   const ushort_t* __restrict__ BT,
                                                   ushort_t* __restrict__ Cb,
                                                   float* __restrict__ Cf,
                                                   const float* __restrict__ bias) {
    const int K = 1024;
    __shared__ ushort_t As[128][40];
    __shared__ ushort_t Bs[128][40];
    int tid = threadIdx.x;
    int wid = tid >> 6, lane = tid & 63;
    int g = lane >> 4, lr = lane & 15;
    int m0 = blockIdx.x * 128, n0 = blockIdx.y * 128;
    int wm = wid >> 1, wn = wid & 1;

    f32x4 acc[4][4] = {};

    int sr = tid >> 1;            // 0..127
    int sk = (tid & 1) * 16;      // 0 or 16
    const ushort_t* Ag = A + (size_t)(m0 + sr) * K + sk;
    const ushort_t* Bg = BT + (size_t)(n0 + sr) * K + sk;

    for (int kt = 0; kt < K / 32; ++kt) {
        bf16x8 a0 = *(const bf16x8*)(Ag + kt * 32);
        bf16x8 a1 = *(const bf16x8*)(Ag + kt * 32 + 8);
        bf16x8 b0 = *(const bf16x8*)(Bg + kt * 32);
        bf16x8 b1 = *(const bf16x8*)(Bg + kt * 32 + 8);
        __syncthreads();
        *(bf16x8*)&As[sr][sk] = a0; *(bf16x8*)&As[sr][sk + 8] = a1;
        *(bf16x8*)&Bs[sr][sk] = b0; *(bf16x8*)&Bs[sr][sk + 8] = b1;
        __syncthreads();
        bf16x8 af[4], bfr[4];
#pragma unroll
        for (int m = 0; m < 4; ++m) af[m]  = *(const bf16x8*)&As[wm * 64 + m * 16 + lr][g * 8];
#pragma unroll
        for (int n = 0; n < 4; ++n) bfr[n] = *(const bf16x8*)&Bs[wn * 64 + n * 16 + lr][g * 8];
#pragma unroll
        for (int m = 0; m < 4; ++m)
#pragma unroll
            for (int n = 0; n < 4; ++n)
                acc[m][n] = __builtin_amdgcn_mfma_f32_16x16x32_bf16(af[m], bfr[n], acc[m][n], 0, 0, 0);
    }

#pragma unroll
    for (int m = 0; m < 4; ++m)
#pragma unroll
        for (int n = 0; n < 4; ++n) {
            int row0 = m0 + wm * 64 + m * 16 + g * 4;
            int col  = n0 + wn * 64 + n * 16 + lr;
#pragma unroll
            for (int r = 0; r < 4; ++r) {
                float v = acc[m][n][r];
                if (OUT_BF16)
                    Cb[(size_t)(row0 + r) * 1024 + col] = f2b(v);
                else
                    Cf[(size_t)(row0 + r) * 1024 + col] = v + bias[col];
            }
        }
}

// ---------------- fused attention: scores+softmax(P out)+PV ----------------
// grid (32 qtiles, 16 heads, 4 batch), block 256 (4 waves, 16 q-rows each)
__global__ __launch_bounds__(256) void attn_kernel(const ushort_t* __restrict__ Qg,
                                                   const ushort_t* __restrict__ Kg,
                                                   const ushort_t* __restrict__ Vg,
                                                   float* __restrict__ Pout,
                                                   ushort_t* __restrict__ Oout) {
    const int S = 2048, D = 1024;
    int b = blockIdx.z, h = blockIdx.y;
    int qt = (int)blockIdx.x;
    int q0 = qt * 64;
    int tid = threadIdx.x, wid = tid >> 6, lane = tid & 63;
    int g = lane >> 4, lr = lane & 15;

    __shared__ ushort_t Ks[64][72];
    __shared__ ushort_t Vt[64][72];
    __shared__ float    Pf[64][68];
    __shared__ ushort_t Pb[64][72];

    const ushort_t* Qb = Qg + (size_t)b * S * D + (size_t)h * 64;
    const ushort_t* Kb = Kg + (size_t)b * S * D + (size_t)h * 64;
    const ushort_t* Vb = Vg + (size_t)b * S * D + (size_t)h * 64;
    float* Pbase = Pout + (((size_t)b * 16 + h) * S + q0) * S;

    // Q fragments (held in regs all kernel)
    bf16x8 qf[2];
    {
        int qrow = q0 + wid * 16 + lr;
#pragma unroll
        for (int kc = 0; kc < 2; ++kc)
            qf[kc] = *(const bf16x8*)(Qb + (size_t)qrow * D + kc * 32 + g * 8);
    }

    float m[4], l[4];
#pragma unroll
    for (int r = 0; r < 4; ++r) { m[r] = -1e30f; l[r] = 0.f; }

    int sr = tid >> 2;          // 0..63
    int sc = (tid & 3) * 16;    // 0,16,32,48

    // ---- phase 1: row stats ----
    for (int tt = 0; tt <= qt; ++tt) {
        bf16x8 k0 = *(const bf16x8*)(Kb + (size_t)(tt * 64 + sr) * D + sc);
        bf16x8 k1 = *(const bf16x8*)(Kb + (size_t)(tt * 64 + sr) * D + sc + 8);
        __syncthreads();
        *(bf16x8*)&Ks[sr][sc] = k0; *(bf16x8*)&Ks[sr][sc + 8] = k1;
        __syncthreads();

        float sv[4][4];
#pragma unroll
        for (int nb = 0; nb < 4; ++nb) {
            f32x4 s = {};
#pragma unroll
            for (int kc = 0; kc < 2; ++kc) {
                bf16x8 kf = *(const bf16x8*)&Ks[nb * 16 + lr][kc * 32 + g * 8];
                s = __builtin_amdgcn_mfma_f32_16x16x32_bf16(qf[kc], kf, s, 0, 0, 0);
            }
#pragma unroll
            for (int r = 0; r < 4; ++r) sv[nb][r] = s[r];
        }
        int qrow = q0 + wid * 16 + g * 4;
#pragma unroll
        for (int r = 0; r < 4; ++r) {
            int q = qrow + r;
            float mx = -1e30f;
#pragma unroll
            for (int nb = 0; nb < 4; ++nb) {
                int t = tt * 64 + nb * 16 + lr;
                float sval = (t <= q) ? sv[nb][r] * 0.125f : -1e30f;
                sv[nb][r] = sval;
                mx = fmaxf(mx, sval);
            }
#pragma unroll
            for (int msk = 1; msk < 16; msk <<= 1) mx = fmaxf(mx, __shfl_xor(mx, msk));
            float mnew = fmaxf(m[r], mx);
            float ssum = 0.f;
#pragma unroll
            for (int nb = 0; nb < 4; ++nb) {
                float sval = sv[nb][r];
                ssum += (sval > -1e29f) ? __expf(sval - mnew) : 0.f;
            }
#pragma unroll
            for (int msk = 1; msk < 16; msk <<= 1) ssum += __shfl_xor(ssum, msk);
            l[r] = l[r] * __expf(m[r] - mnew) + ssum;
            m[r] = mnew;
        }
    }

    float invl[4];
#pragma unroll
    for (int r = 0; r < 4; ++r) invl[r] = 1.0f / l[r];

    f32x4 Oacc[4] = {};

    // ---- phase 2: write P + accumulate O ----
    for (int tt = 0; tt <= qt; ++tt) {
        bf16x8 k0 = *(const bf16x8*)(Kb + (size_t)(tt * 64 + sr) * D + sc);
        bf16x8 k1 = *(const bf16x8*)(Kb + (size_t)(tt * 64 + sr) * D + sc + 8);
        bf16x8 v0 = *(const bf16x8*)(Vb + (size_t)(tt * 64 + sr) * D + sc);
        bf16x8 v1 = *(const bf16x8*)(Vb + (size_t)(tt * 64 + sr) * D + sc + 8);
        __syncthreads();
        *(bf16x8*)&Ks[sr][sc] = k0; *(bf16x8*)&Ks[sr][sc + 8] = k1;
#pragma unroll
        for (int j = 0; j < 8; ++j) {
            Vt[sc + j][sr]     = (ushort_t)v0[j];
            Vt[sc + 8 + j][sr] = (ushort_t)v1[j];
        }
        __syncthreads();

        int qrow = q0 + wid * 16 + g * 4;
#pragma unroll
        for (int nb = 0; nb < 4; ++nb) {
            f32x4 s = {};
#pragma unroll
            for (int kc = 0; kc < 2; ++kc) {
                bf16x8 kf = *(const bf16x8*)&Ks[nb * 16 + lr][kc * 32 + g * 8];
                s = __builtin_amdgcn_mfma_f32_16x16x32_bf16(qf[kc], kf, s, 0, 0, 0);
            }
#pragma unroll
            for (int r = 0; r < 4; ++r) {
                int q = qrow + r;
                int t = tt * 64 + nb * 16 + lr;
                float p = (t <= q) ? __expf(s[r] * 0.125f - m[r]) * invl[r] : 0.f;
                Pf[wid * 16 + g * 4 + r][nb * 16 + lr] = p;
                Pb[wid * 16 + g * 4 + r][nb * 16 + lr] = f2b(p);
            }
        }
        __syncthreads();

        // coalesced P store via LDS
        {
            float* dst = Pbase + (size_t)sr * S + tt * 64 + sc;
#pragma unroll
            for (int j = 0; j < 4; ++j)
                ((float4*)dst)[j] = *(const float4*)&Pf[sr][sc + j * 4];
        }
        // PV MFMA
#pragma unroll
        for (int kc = 0; kc < 2; ++kc) {
            bf16x8 pf = *(const bf16x8*)&Pb[wid * 16 + lr][kc * 32 + g * 8];
#pragma unroll
            for (int nb = 0; nb < 4; ++nb) {
                bf16x8 vf = *(const bf16x8*)&Vt[nb * 16 + lr][kc * 32 + g * 8];
                Oacc[nb] = __builtin_amdgcn_mfma_f32_16x16x32_bf16(pf, vf, Oacc[nb], 0, 0, 0);
            }
        }
        __syncthreads();
    }

    // zero-fill strictly-upper tiles (output must be fully written)
    float4 z = {0.f, 0.f, 0.f, 0.f};
    for (int tt = qt + 1; tt < 32; ++tt) {
        float* dst = Pbase + (size_t)sr * S + tt * 64 + sc;
#pragma unroll
        for (int j = 0; j < 4; ++j) ((float4*)dst)[j] = z;
    }

    // write O (bf16) as [B,S,H*Dh]
#pragma unroll
    for (int nb = 0; nb < 4; ++nb)
#pragma unroll
        for (int r = 0; r < 4; ++r) {
            int q = q0 + wid * 16 + g * 4 + r;
            int d = nb * 16 + lr;
            Oout[((size_t)b * S + q) * D + h * 64 + d] = f2b(Oacc[nb][r]);
        }
}

extern "C" void kernel_launch(void* const* d_in, const int* in_sizes, int n_in,
                              void* d_out, int out_size, void* d_ws, size_t ws_size,
                              hipStream_t stream) {
    const float* x  = (const float*)d_in[0];
    const float* Wq = (const float*)d_in[1];
    const float* Wk = (const float*)d_in[2];
    const float* Wv = (const float*)d_in[3];
    const float* Wo = (const float*)d_in[4];
    const float* bo = (const float*)d_in[5];

    float* out  = (float*)d_out;
    float* Pout = out + (size_t)8388608; // attn_probs region

    char* ws = (char*)d_ws;
    ushort_t* xb    = (ushort_t*)(ws);
    ushort_t* wqb   = (ushort_t*)(ws + 16777216);
    ushort_t* wkb   = (ushort_t*)(ws + 18874368);
    ushort_t* wvb   = (ushort_t*)(ws + 20971520);
    ushort_t* wob   = (ushort_t*)(ws + 23068672);
    ushort_t* Qw    = (ushort_t*)(ws + 25165824);
    ushort_t* Kw    = (ushort_t*)(ws + 41943040);
    ushort_t* Vw    = (ushort_t*)(ws + 58720256);
    ushort_t* attnb = (ushort_t*)(ws + 75497472);

    // 1. dtype conversions
    convert_x_kernel<<<8192, 256, 0, stream>>>(x, xb, 2097152);
    transpose_w_kernel<<<dim3(32, 32), dim3(32, 8), 0, stream>>>(Wq, wqb);
    transpose_w_kernel<<<dim3(32, 32), dim3(32, 8), 0, stream>>>(Wk, wkb);
    transpose_w_kernel<<<dim3(32, 32), dim3(32, 8), 0, stream>>>(Wv, wvb);
    transpose_w_kernel<<<dim3(32, 32), dim3(32, 8), 0, stream>>>(Wo, wob);

    // 2. QKV projections
    gemm_kernel<1><<<dim3(64, 8), 256, 0, stream>>>(xb, wqb, Qw, nullptr, nullptr);
    gemm_kernel<1><<<dim3(64, 8), 256, 0, stream>>>(xb, wkb, Kw, nullptr, nullptr);
    gemm_kernel<1><<<dim3(64, 8), 256, 0, stream>>>(xb, wvb, Vw, nullptr, nullptr);

    // 3. attention (writes attn_probs fp32 + context bf16)
    attn_kernel<<<dim3(32, 16, 4), 256, 0, stream>>>(Qw, Kw, Vw, Pout, attnb);

    // 4. output projection + bias (fp32 out)
    gemm_kernel<0><<<dim3(64, 8), 256, 0, stream>>>(attnb, wob, nullptr, out, bo);
}